// Round 10
// baseline (277.466 us; speedup 1.0000x reference)
//
#include <hip/hip_runtime.h>
#include <math.h>

#define NB 32
#define LQ 2048
#define LK 2048
#define HD 1024
#define AD 512
#define QCH 32   // streaming blocks per batch (1024 total)

// =====================================================================
// K1: 512 threads/block.
//  blocks 0..1023   : stream 64 query rows -> partial chunk (atomicExch,
//                     write-through); last block per batch = finisher:
//                     s_q -> qsum -> wk_eff[b] in-block.
//  blocks 1024..1039: wv_eff[h] = Wk[h,:]·Wv
//  block  1040      : c_v = bk·Wv + bv
// =====================================================================
__global__ void __launch_bounds__(512)
k1_stream(const float* __restrict__ query, const float* __restrict__ Wq,
          const float* __restrict__ bq, const float* __restrict__ Wk,
          const float* __restrict__ Wv, const float* __restrict__ bk,
          const float* __restrict__ bv,
          float* __restrict__ partial, float* __restrict__ wk_eff,
          float* __restrict__ wv_eff, float* __restrict__ c_v,
          int* __restrict__ cnt) {
    __shared__ float sq[HD];     // finisher: s_q (4 KB)
    __shared__ float qs[AD];     // finisher: qsum (2 KB)
    __shared__ int isLast;
    const int bid = blockIdx.x;
    const int t = threadIdx.x;   // 512

    if (bid < NB * QCH) {
        int b = bid / QCH, qc = bid % QCH;
        const int QPC = LQ / QCH;            // 64 rows
        // each thread owns float2 column 2t..2t+1 (8 B/lane, coalesced)
        float2 a0 = {0.f,0.f}, a1 = {0.f,0.f}, a2 = {0.f,0.f}, a3 = {0.f,0.f};
        const float2* src = (const float2*)(query + ((size_t)b * LQ + (size_t)qc * QPC) * HD);
        for (int q = 0; q < QPC; q += 4) {
            float2 v0 = src[(size_t)(q + 0) * (HD / 2) + t];
            float2 v1 = src[(size_t)(q + 1) * (HD / 2) + t];
            float2 v2 = src[(size_t)(q + 2) * (HD / 2) + t];
            float2 v3 = src[(size_t)(q + 3) * (HD / 2) + t];
            a0.x += v0.x; a0.y += v0.y;
            a1.x += v1.x; a1.y += v1.y;
            a2.x += v2.x; a2.y += v2.y;
            a3.x += v3.x; a3.y += v3.y;
        }
        float sx = (a0.x + a1.x) + (a2.x + a3.x);
        float sy = (a0.y + a1.y) + (a2.y + a3.y);
        // write-through (coherent) stores of our chunk
        float* dst = partial + ((size_t)qc * NB + b) * HD + 2 * t;
        atomicExch(dst,     sx);
        atomicExch(dst + 1, sy);
        // drain this wave's stores to the coherent point, then count
        asm volatile("s_waitcnt vmcnt(0)" ::: "memory");
        __syncthreads();
        if (t == 0) {
            int old = atomicAdd(&cnt[b], 1);
            isLast = (old == QCH - 1) ? 1 : 0;
        }
        __syncthreads();
        if (!isLast) return;

        // ---------------- finisher for batch b ----------------
        // Phase A: s_q[h] = sum over qc of partial (coherent reads)
        #pragma unroll
        for (int c = 0; c < 2; ++c) {
            int h = t + c * 512;
            float a = 0.f;
            #pragma unroll 4
            for (int q2 = 0; q2 < QCH; ++q2)
                a += atomicAdd(partial + ((size_t)q2 * NB + b) * HD + h, 0.0f);
            sq[h] = a;
        }
        __syncthreads();
        // Phase B: qsum[a] = s_q·Wq[:,a] + LQ*bq[a]  (one column per thread)
        {
            const float* wp = Wq + t;                // a = t (512 columns)
            double c0 = 0.0, c1 = 0.0, c2 = 0.0, c3 = 0.0;
            for (int h = 0; h < HD; h += 4) {
                c0 += (double)sq[h]     * wp[(size_t)h * AD];
                c1 += (double)sq[h + 1] * wp[(size_t)(h + 1) * AD];
                c2 += (double)sq[h + 2] * wp[(size_t)(h + 2) * AD];
                c3 += (double)sq[h + 3] * wp[(size_t)(h + 3) * AD];
            }
            qs[t] = (float)(((c0 + c1) + (c2 + c3)) + (double)LQ * (double)bq[t]);
        }
        __syncthreads();
        // Phase C: wk_eff[b][h] = qsum·Wk[h,:]  (8 waves x 128 rows, 2 in flight)
        {
            int w = t >> 6, lane = t & 63;
            const float4* qs4 = (const float4*)qs;
            for (int r = 0; r < 128; r += 2) {
                int h0 = w * 128 + r;
                const float4* r0 = (const float4*)(Wk + (size_t)h0 * AD);
                const float4* r1 = (const float4*)(Wk + (size_t)(h0 + 1) * AD);
                double d0 = 0.0, d1 = 0.0;
                #pragma unroll
                for (int j = 0; j < 2; ++j) {
                    int f = lane + 64 * j;
                    float4 w0 = r0[f];
                    float4 w1 = r1[f];
                    float4 q4 = qs4[f];
                    d0 += (double)w0.x * q4.x + (double)w0.y * q4.y
                        + (double)w0.z * q4.z + (double)w0.w * q4.w;
                    d1 += (double)w1.x * q4.x + (double)w1.y * q4.y
                        + (double)w1.z * q4.z + (double)w1.w * q4.w;
                }
                #pragma unroll
                for (int off = 32; off > 0; off >>= 1) {
                    d0 += __shfl_down(d0, off);
                    d1 += __shfl_down(d1, off);
                }
                if (lane == 0) {
                    wk_eff[(size_t)b * HD + h0]     = (float)d0;   // plain store:
                    wk_eff[(size_t)b * HD + h0 + 1] = (float)d1;   // consumed after kernel boundary
                }
            }
        }
    } else if (bid < NB * QCH + 16) {
        int w = t >> 6, lane = t & 63;
        int gw = (bid - NB * QCH) * 8 + w;           // 0..127, 8 rows each
        const float4* vv = (const float4*)Wv;
        for (int r = 0; r < 8; ++r) {
            int h = gw * 8 + r;
            const float4* wr = (const float4*)(Wk + (size_t)h * AD);
            double acc = 0.0;
            #pragma unroll
            for (int j = 0; j < 2; ++j) {
                int f = lane + 64 * j;               // covers AD/4 = 128
                float4 w4 = wr[f];
                float4 v4 = vv[f];
                acc += (double)w4.x * v4.x + (double)w4.y * v4.y
                     + (double)w4.z * v4.z + (double)w4.w * v4.w;
            }
            #pragma unroll
            for (int off = 32; off > 0; off >>= 1) acc += __shfl_down(acc, off);
            if (lane == 0) wv_eff[h] = (float)acc;
        }
    } else if (t < 64) {
        int lane = t;
        const float4* br = (const float4*)bk;
        const float4* vv = (const float4*)Wv;
        double acc = 0.0;
        #pragma unroll
        for (int j = 0; j < 2; ++j) {
            int f = lane + 64 * j;
            float4 b4 = br[f];
            float4 v4 = vv[f];
            acc += (double)b4.x * v4.x + (double)b4.y * v4.y
                 + (double)b4.z * v4.z + (double)b4.w * v4.w;
        }
        #pragma unroll
        for (int off = 32; off > 0; off >>= 1) acc += __shfl_down(acc, off);
        if (lane == 0) c_v[0] = (float)(acc + (double)bv[0]);
    }
}

// =====================================================================
// K2: 2048 blocks x 256 threads, 32 keys each:
//   scores = key·wk_eff[b], vvals = key·wv_eff + c_v  (atomicExch writes)
//   last of 64 blocks per batch folds softmax -> out[b]
// =====================================================================
__global__ void __launch_bounds__(256)
k2_scores(const float* __restrict__ key, const float* __restrict__ wk_eff,
          const float* __restrict__ wv_eff, const float* __restrict__ c_v,
          float* __restrict__ scores, float* __restrict__ vvals,
          int* __restrict__ cnt2, float* __restrict__ out) {
    __shared__ float lwk[HD];
    __shared__ float lwv[HD];
    __shared__ int isLast;
    __shared__ float smax_sh[4];
    __shared__ double num_sh[4], den_sh[4];
    const int bid = blockIdx.x;
    const int b = bid >> 6;              // 64 blocks per batch
    const int k0 = (bid & 63) * 32;
    const int t = threadIdx.x;
    for (int i = t; i < HD; i += 256) {
        lwk[i] = wk_eff[(size_t)b * HD + i];
        lwv[i] = wv_eff[i];
    }
    __syncthreads();
    int w = t >> 6, lane = t & 63;
    double cv = (double)c_v[0];
    const float4* lwk4 = (const float4*)lwk;
    const float4* lwv4 = (const float4*)lwv;
    for (int rp = 0; rp < 2; ++rp) {
        int k = k0 + w * 8 + rp * 4;
        const float4* kr0 = (const float4*)(key + ((size_t)b * LK + k) * HD);
        const float4* kr1 = kr0 + (HD / 4);
        const float4* kr2 = kr0 + 2 * (HD / 4);
        const float4* kr3 = kr0 + 3 * (HD / 4);
        double sc0 = 0.0, vv0 = 0.0, sc1 = 0.0, vv1 = 0.0;
        double sc2 = 0.0, vv2 = 0.0, sc3 = 0.0, vv3 = 0.0;
        #pragma unroll
        for (int j = 0; j < 4; ++j) {
            int f = lane + 64 * j;
            float4 k0v = kr0[f];
            float4 k1v = kr1[f];
            float4 k2v = kr2[f];
            float4 k3v = kr3[f];
            float4 wk4 = lwk4[f];
            float4 wv4 = lwv4[f];
            sc0 += (double)k0v.x * wk4.x + (double)k0v.y * wk4.y
                 + (double)k0v.z * wk4.z + (double)k0v.w * wk4.w;
            vv0 += (double)k0v.x * wv4.x + (double)k0v.y * wv4.y
                 + (double)k0v.z * wv4.z + (double)k0v.w * wv4.w;
            sc1 += (double)k1v.x * wk4.x + (double)k1v.y * wk4.y
                 + (double)k1v.z * wk4.z + (double)k1v.w * wk4.w;
            vv1 += (double)k1v.x * wv4.x + (double)k1v.y * wv4.y
                 + (double)k1v.z * wv4.z + (double)k1v.w * wv4.w;
            sc2 += (double)k2v.x * wk4.x + (double)k2v.y * wk4.y
                 + (double)k2v.z * wk4.z + (double)k2v.w * wk4.w;
            vv2 += (double)k2v.x * wv4.x + (double)k2v.y * wv4.y
                 + (double)k2v.z * wv4.z + (double)k2v.w * wv4.w;
            sc3 += (double)k3v.x * wk4.x + (double)k3v.y * wk4.y
                 + (double)k3v.z * wk4.z + (double)k3v.w * wk4.w;
            vv3 += (double)k3v.x * wv4.x + (double)k3v.y * wv4.y
                 + (double)k3v.z * wv4.z + (double)k3v.w * wv4.w;
        }
        #pragma unroll
        for (int off = 32; off > 0; off >>= 1) {
            sc0 += __shfl_down(sc0, off);
            vv0 += __shfl_down(vv0, off);
            sc1 += __shfl_down(sc1, off);
            vv1 += __shfl_down(vv1, off);
            sc2 += __shfl_down(sc2, off);
            vv2 += __shfl_down(vv2, off);
            sc3 += __shfl_down(sc3, off);
            vv3 += __shfl_down(vv3, off);
        }
        if (lane == 0) {
            size_t base = (size_t)b * LK + k;
            atomicExch(&scores[base],     (float)sc0);
            atomicExch(&vvals [base],     (float)(vv0 + cv));
            atomicExch(&scores[base + 1], (float)sc1);
            atomicExch(&vvals [base + 1], (float)(vv1 + cv));
            atomicExch(&scores[base + 2], (float)sc2);
            atomicExch(&vvals [base + 2], (float)(vv2 + cv));
            atomicExch(&scores[base + 3], (float)sc3);
            atomicExch(&vvals [base + 3], (float)(vv3 + cv));
        }
    }
    asm volatile("s_waitcnt vmcnt(0)" ::: "memory");
    __syncthreads();
    if (t == 0) {
        int old = atomicAdd(&cnt2[b], 1);
        isLast = (old == 63) ? 1 : 0;
    }
    __syncthreads();
    if (!isLast) return;

    // ---------------- fold: softmax + weighted sum for batch b ----------------
    float s8[8], v8[8];
    #pragma unroll
    for (int i = 0; i < 8; ++i) {
        int k = t + i * 256;
        s8[i] = atomicAdd(&scores[(size_t)b * LK + k], 0.0f);   // coherent read
        v8[i] = atomicAdd(&vvals [(size_t)b * LK + k], 0.0f);
    }
    float m = s8[0];
    #pragma unroll
    for (int i = 1; i < 8; ++i) m = fmaxf(m, s8[i]);
    #pragma unroll
    for (int off = 32; off > 0; off >>= 1) m = fmaxf(m, __shfl_down(m, off));
    if (lane == 0) smax_sh[w] = m;
    __syncthreads();
    float gm = fmaxf(fmaxf(smax_sh[0], smax_sh[1]), fmaxf(smax_sh[2], smax_sh[3]));
    double num = 0.0, den = 0.0;
    #pragma unroll
    for (int i = 0; i < 8; ++i) {
        double e = exp((double)s8[i] - (double)gm);
        den += e;
        num += e * (double)v8[i];
    }
    #pragma unroll
    for (int off = 32; off > 0; off >>= 1) {
        num += __shfl_down(num, off);
        den += __shfl_down(den, off);
    }
    if (lane == 0) { num_sh[w] = num; den_sh[w] = den; }
    __syncthreads();
    if (t == 0) {
        double N = num_sh[0] + num_sh[1] + num_sh[2] + num_sh[3];
        double D = den_sh[0] + den_sh[1] + den_sh[2] + den_sh[3];
        out[b] = (float)(N / D);
    }
}

extern "C" void kernel_launch(void* const* d_in, const int* in_sizes, int n_in,
                              void* d_out, int out_size, void* d_ws, size_t ws_size,
                              hipStream_t stream) {
    const float* query = (const float*)d_in[0];
    const float* key   = (const float*)d_in[1];
    const float* Wq    = (const float*)d_in[2];
    const float* bq    = (const float*)d_in[3];
    const float* Wk    = (const float*)d_in[4];
    const float* bk    = (const float*)d_in[5];
    const float* Wv    = (const float*)d_in[6];
    const float* bv    = (const float*)d_in[7];
    float* out = (float*)d_out;

    float* ws = (float*)d_ws;
    size_t off = 0;
    float* partial = ws + off; off += (size_t)QCH * NB * HD;   // 4 MB
    float* wk_eff  = ws + off; off += (size_t)NB * HD;
    float* wv_eff  = ws + off; off += (size_t)HD;
    float* c_v     = ws + off; off += 1;
    float* scores  = ws + off; off += (size_t)NB * LK;
    float* vvals   = ws + off; off += (size_t)NB * LK;
    int*   cnt     = (int*)(ws + off); off += 2 * NB;          // cnt[0..31]=K1, cnt[32..63]=K2

    hipMemsetAsync(cnt, 0, 2 * NB * sizeof(int), stream);
    hipLaunchKernelGGL(k1_stream, dim3(NB * QCH + 16 + 1), dim3(512), 0, stream,
                       query, Wq, bq, Wk, Wv, bk, bv,
                       partial, wk_eff, wv_eff, c_v, cnt);
    hipLaunchKernelGGL(k2_scores, dim3(NB * (LK / 32)), dim3(256), 0, stream,
                       key, wk_eff, wv_eff, c_v, scores, vvals, cnt + NB, out);
}

// Round 11
// 155.572 us; speedup vs baseline: 1.7835x; 1.7835x over previous
//
#include <hip/hip_runtime.h>
#include <math.h>

#define NB 32
#define LQ 2048
#define LK 2048
#define HD 1024
#define AD 512
#define QCH 32   // q-chunks for first-stage query reduction (1024 stream blocks)

// =====================================================================
// K1: blocks 0..1023   : partial[qc][b][h] = sum over 64-row q-chunk (4 rows in flight)
//     blocks 1024..1039: wv_eff[h] = Wk[h,:]·Wv (wave-per-row)
//     block  1040      : c_v = bk·Wv + bv
// (proven round-9 kernel, plain stores only)
// =====================================================================
__global__ void __launch_bounds__(256)
k1_stream(const float* __restrict__ query, const float* __restrict__ Wk,
          const float* __restrict__ Wv, const float* __restrict__ bk,
          const float* __restrict__ bv, float* __restrict__ partial,
          float* __restrict__ wv_eff, float* __restrict__ c_v) {
    const int bid = blockIdx.x;
    const int t = threadIdx.x;
    if (bid < NB * QCH) {
        int b = bid / QCH, qc = bid % QCH;
        const int QPC = LQ / QCH;        // 64 rows per chunk
        float4 a0 = {0.f,0.f,0.f,0.f}, a1 = {0.f,0.f,0.f,0.f};
        float4 a2 = {0.f,0.f,0.f,0.f}, a3 = {0.f,0.f,0.f,0.f};
        const float4* src = (const float4*)(query + ((size_t)b * LQ + (size_t)qc * QPC) * HD);
        for (int q = 0; q < QPC; q += 4) {
            float4 v0 = src[(size_t)(q + 0) * (HD / 4) + t];
            float4 v1 = src[(size_t)(q + 1) * (HD / 4) + t];
            float4 v2 = src[(size_t)(q + 2) * (HD / 4) + t];
            float4 v3 = src[(size_t)(q + 3) * (HD / 4) + t];
            a0.x += v0.x; a0.y += v0.y; a0.z += v0.z; a0.w += v0.w;
            a1.x += v1.x; a1.y += v1.y; a1.z += v1.z; a1.w += v1.w;
            a2.x += v2.x; a2.y += v2.y; a2.z += v2.z; a2.w += v2.w;
            a3.x += v3.x; a3.y += v3.y; a3.z += v3.z; a3.w += v3.w;
        }
        float4 acc = {(a0.x + a1.x) + (a2.x + a3.x), (a0.y + a1.y) + (a2.y + a3.y),
                      (a0.z + a1.z) + (a2.z + a3.z), (a0.w + a1.w) + (a2.w + a3.w)};
        ((float4*)(partial + ((size_t)qc * NB + b) * HD))[t] = acc;
    } else if (bid < NB * QCH + 16) {
        int w = t >> 6, lane = t & 63;
        int gw = (bid - NB * QCH) * 4 + w;           // 0..63
        const float4* vv = (const float4*)Wv;
        for (int r = 0; r < 16; ++r) {
            int h = gw * 16 + r;
            const float4* wr = (const float4*)(Wk + (size_t)h * AD);
            double acc = 0.0;
            #pragma unroll
            for (int j = 0; j < 2; ++j) {
                int f = lane + 64 * j;               // covers AD/4 = 128
                float4 w4 = wr[f];
                float4 v4 = vv[f];
                acc += (double)w4.x * v4.x + (double)w4.y * v4.y
                     + (double)w4.z * v4.z + (double)w4.w * v4.w;
            }
            #pragma unroll
            for (int off = 32; off > 0; off >>= 1) acc += __shfl_down(acc, off);
            if (lane == 0) wv_eff[h] = (float)acc;
        }
    } else if (t < 64) {
        int lane = t;
        const float4* br = (const float4*)bk;
        const float4* vv = (const float4*)Wv;
        double acc = 0.0;
        #pragma unroll
        for (int j = 0; j < 2; ++j) {
            int f = lane + 64 * j;
            float4 b4 = br[f];
            float4 v4 = vv[f];
            acc += (double)b4.x * v4.x + (double)b4.y * v4.y
                 + (double)b4.z * v4.z + (double)b4.w * v4.w;
        }
        #pragma unroll
        for (int off = 32; off > 0; off >>= 1) acc += __shfl_down(acc, off);
        if (lane == 0) c_v[0] = (float)(acc + (double)bv[0]);
    }
}

// =====================================================================
// K2: 256 blocks: b = bid>>3, a-chunk of 64 = (bid&7)*64.
//   Phase A: s_q[b][:] into LDS; Phase B: qsum chunk. (proven round-3/9)
// =====================================================================
__global__ void __launch_bounds__(256)
k2_qsum(const float* __restrict__ partial, const float* __restrict__ Wq,
        const float* __restrict__ bq, float* __restrict__ qsum) {
    __shared__ float sq[HD];
    __shared__ double red[4][64];
    int b = blockIdx.x >> 3;
    int a0 = (blockIdx.x & 7) * 64;
    int t = threadIdx.x;

    #pragma unroll
    for (int c = 0; c < 4; ++c) {
        int h = t + c * 256;
        float acc = 0.f;
        #pragma unroll 4
        for (int qc = 0; qc < QCH; ++qc)
            acc += partial[((size_t)qc * NB + b) * HD + h];
        sq[h] = acc;
    }
    __syncthreads();

    int w = t >> 6, lane = t & 63;
    int a = a0 + lane;
    const float* wp = Wq + a;
    double c0 = 0.0, c1 = 0.0, c2 = 0.0, c3 = 0.0;
    int hbase = w * 256;
    for (int i = 0; i < 256; i += 4) {
        int h = hbase + i;
        c0 += (double)sq[h]     * wp[(size_t)h * AD];
        c1 += (double)sq[h + 1] * wp[(size_t)(h + 1) * AD];
        c2 += (double)sq[h + 2] * wp[(size_t)(h + 2) * AD];
        c3 += (double)sq[h + 3] * wp[(size_t)(h + 3) * AD];
    }
    red[w][lane] = ((c0 + c1) + (c2 + c3));
    __syncthreads();
    if (t < 64) {
        double s = red[0][t] + red[1][t] + red[2][t] + red[3][t];
        qsum[(size_t)b * AD + a0 + t] = (float)(s + (double)LQ * bq[a0 + t]);
    }
}

// =====================================================================
// K3: 2048 blocks x 4 waves, 4 rows per wave: wk_eff[b][h] = qsum[b]·Wk[h,:]
// (proven round-9)
// =====================================================================
__global__ void __launch_bounds__(256)
k3_weff(const float* __restrict__ qsum, const float* __restrict__ Wk,
        float* __restrict__ wk_eff) {
    int w = threadIdx.x >> 6, lane = threadIdx.x & 63;
    int widx = blockIdx.x * 4 + w;                   // 8192 waves
    int base = widx * 4;                             // 4 rows each
    for (int r = 0; r < 4; r += 2) {
        int idx0 = base + r;                         // 0..32767
        int b = idx0 >> 10, h0 = idx0 & (HD - 1);
        const float4* r0 = (const float4*)(Wk + (size_t)h0 * AD);
        const float4* r1 = (const float4*)(Wk + (size_t)(h0 + 1) * AD);
        const float4* qs = (const float4*)(qsum + (size_t)b * AD);
        double a0 = 0.0, a1 = 0.0;
        #pragma unroll
        for (int j = 0; j < 2; ++j) {
            int f = lane + 64 * j;
            float4 w0 = r0[f];
            float4 w1 = r1[f];
            float4 q4 = qs[f];
            a0 += (double)w0.x * q4.x + (double)w0.y * q4.y
                + (double)w0.z * q4.z + (double)w0.w * q4.w;
            a1 += (double)w1.x * q4.x + (double)w1.y * q4.y
                + (double)w1.z * q4.z + (double)w1.w * q4.w;
        }
        #pragma unroll
        for (int off = 32; off > 0; off >>= 1) {
            a0 += __shfl_down(a0, off);
            a1 += __shfl_down(a1, off);
        }
        if (lane == 0) {
            wk_eff[idx0]     = (float)a0;
            wk_eff[idx0 + 1] = (float)a1;
        }
    }
}

// =====================================================================
// K4: 2048 blocks, 32 keys each: compute scores/vvals IN REGISTERS,
//   reduce to per-block online-softmax triple (m, D, N) in f64,
//   publish 24 B via 64-bit atomicExch; counter-elected last block
//   per batch merges 64 triples -> out[b]. NO bulk cross-block data.
// =====================================================================
__global__ void __launch_bounds__(256)
k4_scores(const float* __restrict__ key, const float* __restrict__ wk_eff,
          const float* __restrict__ wv_eff, const float* __restrict__ c_v,
          double* __restrict__ pub, int* __restrict__ cnt,
          float* __restrict__ out) {
    __shared__ float lwk[HD];
    __shared__ float lwv[HD];
    __shared__ double sLDS[32];
    __shared__ double vLDS[32];
    __shared__ int isLast;
    const int bid = blockIdx.x;
    const int b = bid >> 6;              // 64 blocks per batch
    const int j = bid & 63;              // block index within batch
    const int k0 = j * 32;
    const int t = threadIdx.x;
    for (int i = t; i < HD; i += 256) {
        lwk[i] = wk_eff[(size_t)b * HD + i];
        lwv[i] = wv_eff[i];
    }
    __syncthreads();
    int w = t >> 6, lane = t & 63;
    double cv = (double)c_v[0];
    const float4* lwk4 = (const float4*)lwk;
    const float4* lwv4 = (const float4*)lwv;
    for (int rp = 0; rp < 2; ++rp) {
        int k = k0 + w * 8 + rp * 4;
        const float4* kr0 = (const float4*)(key + ((size_t)b * LK + k) * HD);
        const float4* kr1 = kr0 + (HD / 4);
        const float4* kr2 = kr0 + 2 * (HD / 4);
        const float4* kr3 = kr0 + 3 * (HD / 4);
        double sc0 = 0.0, vv0 = 0.0, sc1 = 0.0, vv1 = 0.0;
        double sc2 = 0.0, vv2 = 0.0, sc3 = 0.0, vv3 = 0.0;
        #pragma unroll
        for (int jj = 0; jj < 4; ++jj) {
            int f = lane + 64 * jj;
            float4 k0v = kr0[f];
            float4 k1v = kr1[f];
            float4 k2v = kr2[f];
            float4 k3v = kr3[f];
            float4 wk4 = lwk4[f];
            float4 wv4 = lwv4[f];
            sc0 += (double)k0v.x * wk4.x + (double)k0v.y * wk4.y
                 + (double)k0v.z * wk4.z + (double)k0v.w * wk4.w;
            vv0 += (double)k0v.x * wv4.x + (double)k0v.y * wv4.y
                 + (double)k0v.z * wv4.z + (double)k0v.w * wv4.w;
            sc1 += (double)k1v.x * wk4.x + (double)k1v.y * wk4.y
                 + (double)k1v.z * wk4.z + (double)k1v.w * wk4.w;
            vv1 += (double)k1v.x * wv4.x + (double)k1v.y * wv4.y
                 + (double)k1v.z * wv4.z + (double)k1v.w * wv4.w;
            sc2 += (double)k2v.x * wk4.x + (double)k2v.y * wk4.y
                 + (double)k2v.z * wk4.z + (double)k2v.w * wk4.w;
            vv2 += (double)k2v.x * wv4.x + (double)k2v.y * wv4.y
                 + (double)k2v.z * wv4.z + (double)k2v.w * wv4.w;
            sc3 += (double)k3v.x * wk4.x + (double)k3v.y * wk4.y
                 + (double)k3v.z * wk4.z + (double)k3v.w * wk4.w;
            vv3 += (double)k3v.x * wv4.x + (double)k3v.y * wv4.y
                 + (double)k3v.z * wv4.z + (double)k3v.w * wv4.w;
        }
        #pragma unroll
        for (int off = 32; off > 0; off >>= 1) {
            sc0 += __shfl_down(sc0, off);
            vv0 += __shfl_down(vv0, off);
            sc1 += __shfl_down(sc1, off);
            vv1 += __shfl_down(vv1, off);
            sc2 += __shfl_down(sc2, off);
            vv2 += __shfl_down(vv2, off);
            sc3 += __shfl_down(sc3, off);
            vv3 += __shfl_down(vv3, off);
        }
        if (lane == 0) {
            int kl = w * 8 + rp * 4;                 // local key index 0..31
            sLDS[kl]     = sc0;  vLDS[kl]     = vv0 + cv;
            sLDS[kl + 1] = sc1;  vLDS[kl + 1] = vv1 + cv;
            sLDS[kl + 2] = sc2;  vLDS[kl + 2] = vv2 + cv;
            sLDS[kl + 3] = sc3;  vLDS[kl + 3] = vv3 + cv;
        }
    }
    __syncthreads();

    // wave 0: local online-softmax triple over the block's 32 keys (f64)
    if (w == 0) {
        double s = sLDS[lane & 31];
        double m = s;
        #pragma unroll
        for (int off = 32; off > 0; off >>= 1) m = fmax(m, __shfl_down(m, off));
        m = __shfl(m, 0);
        double e = (lane < 32) ? exp(s - m) : 0.0;
        double ev = (lane < 32) ? e * vLDS[lane] : 0.0;
        #pragma unroll
        for (int off = 32; off > 0; off >>= 1) {
            e  += __shfl_down(e, off);
            ev += __shfl_down(ev, off);
        }
        if (lane == 0) {
            unsigned long long* p =
                (unsigned long long*)(pub + ((size_t)b * 64 + j) * 3);
            atomicExch(&p[0], __double_as_longlong(m));
            atomicExch(&p[1], __double_as_longlong(e));
            atomicExch(&p[2], __double_as_longlong(ev));
            asm volatile("s_waitcnt vmcnt(0)" ::: "memory");
            int old = atomicAdd(&cnt[b], 1);
            isLast = (old == 63) ? 1 : 0;
        }
    }
    __syncthreads();
    if (!isLast) return;

    // elected last block: merge the 64 triples of batch b (wave 0 only)
    if (w == 0) {
        unsigned long long* pb =
            (unsigned long long*)(pub + (size_t)b * 64 * 3);
        double mj = __longlong_as_double(atomicAdd(&pb[lane * 3 + 0], 0ull));
        double Dj = __longlong_as_double(atomicAdd(&pb[lane * 3 + 1], 0ull));
        double Nj = __longlong_as_double(atomicAdd(&pb[lane * 3 + 2], 0ull));
        double m = mj;
        #pragma unroll
        for (int off = 32; off > 0; off >>= 1) m = fmax(m, __shfl_down(m, off));
        m = __shfl(m, 0);
        double sc = exp(mj - m);
        double D = Dj * sc;
        double N = Nj * sc;
        #pragma unroll
        for (int off = 32; off > 0; off >>= 1) {
            D += __shfl_down(D, off);
            N += __shfl_down(N, off);
        }
        if (lane == 0) out[b] = (float)(N / D);
    }
}

extern "C" void kernel_launch(void* const* d_in, const int* in_sizes, int n_in,
                              void* d_out, int out_size, void* d_ws, size_t ws_size,
                              hipStream_t stream) {
    const float* query = (const float*)d_in[0];
    const float* key   = (const float*)d_in[1];
    const float* Wq    = (const float*)d_in[2];
    const float* bq    = (const float*)d_in[3];
    const float* Wk    = (const float*)d_in[4];
    const float* bk    = (const float*)d_in[5];
    const float* Wv    = (const float*)d_in[6];
    const float* bv    = (const float*)d_in[7];
    float* out = (float*)d_out;

    float* ws = (float*)d_ws;
    size_t off = 0;
    float* partial = ws + off; off += (size_t)QCH * NB * HD;   // 4 MB
    float* qsum    = ws + off; off += (size_t)NB * AD;
    float* wk_eff  = ws + off; off += (size_t)NB * HD;
    float* wv_eff  = ws + off; off += (size_t)HD;
    float* c_v     = ws + off; off += 2;                       // pad to even
    double* pub    = (double*)(ws + off); off += (size_t)NB * 64 * 3 * 2;  // f64 triples
    int*   cnt     = (int*)(ws + off); off += NB;

    hipMemsetAsync(cnt, 0, NB * sizeof(int), stream);
    hipLaunchKernelGGL(k1_stream, dim3(NB * QCH + 16 + 1), dim3(256), 0, stream,
                       query, Wk, Wv, bk, bv, partial, wv_eff, c_v);
    hipLaunchKernelGGL(k2_qsum, dim3(256), dim3(256), 0, stream,
                       partial, Wq, bq, qsum);
    hipLaunchKernelGGL(k3_weff, dim3(2048), dim3(256), 0, stream,
                       qsum, Wk, wk_eff);
    hipLaunchKernelGGL(k4_scores, dim3(NB * (LK / 32)), dim3(256), 0, stream,
                       key, wk_eff, wv_eff, c_v, pub, cnt, out);
}